// Round 1
// baseline (502.554 us; speedup 1.0000x reference)
//
#include <hip/hip_runtime.h>

#define M_ROWS 16384
#define DIMX   1024
#define CD     12
#define KCB    4096

// ---------------- Kernel A: h = x @ W_in + b_in  (wave per row) ----------------
__global__ __launch_bounds__(256) void k_hproj(
    const float* __restrict__ x, const float* __restrict__ Win,
    const float* __restrict__ bin, float* __restrict__ h)
{
  __shared__ __align__(16) float w[DIMX * CD];
  // stage W_in (1024x12 f32 = 48 KiB) into LDS, vectorized
  for (int i = threadIdx.x; i < DIMX * CD / 4; i += 256)
    reinterpret_cast<float4*>(w)[i] = reinterpret_cast<const float4*>(Win)[i];
  __syncthreads();

  const int wave = threadIdx.x >> 6;
  const int lane = threadIdx.x & 63;
  const int row  = blockIdx.x * 4 + wave;

  const float4* xr = reinterpret_cast<const float4*>(x + (size_t)row * DIMX);
  float acc[CD];
#pragma unroll
  for (int d = 0; d < CD; ++d) acc[d] = 0.f;

#pragma unroll
  for (int k = 0; k < 4; ++k) {
    float4 xv = xr[lane + 64 * k];          // coalesced 1 KiB / instr
    const float* wp = &w[(lane + 64 * k) * 4 * CD];  // 48 consecutive floats, 16B aligned
    float xe[4] = {xv.x, xv.y, xv.z, xv.w};
#pragma unroll
    for (int e = 0; e < 4; ++e)
#pragma unroll
      for (int d = 0; d < CD; ++d)
        acc[d] = fmaf(xe[e], wp[e * CD + d], acc[d]);
  }
  // butterfly reduce 12 partials across the 64-lane wave
#pragma unroll
  for (int ofs = 1; ofs < 64; ofs <<= 1)
#pragma unroll
    for (int d = 0; d < CD; ++d)
      acc[d] += __shfl_xor(acc[d], ofs, 64);

  if (lane == 0) {
#pragma unroll
    for (int d = 0; d < CD; ++d)
      h[(size_t)row * CD + d] = acc[d] + bin[d];
  }
}

// ------- Kernel B: per-row sign/out/index/entropy + factorized avg_prob -------
__global__ __launch_bounds__(256) void k_main(
    const float* __restrict__ h, const float* __restrict__ Wout,
    const float* __restrict__ bout, float* __restrict__ out,
    float* __restrict__ oidx, float* __restrict__ hist,
    float* __restrict__ pse, float* __restrict__ com)
{
  __shared__ float sh[CD], sq[CD];
  __shared__ __align__(16) float sA[64];
  __shared__ float sB[64];
  __shared__ float sr0[CD], sr1[CD];
  const int t = threadIdx.x;

  // thread t owns output columns 4t..4t+3 : W_out fragment in registers (48 regs)
  float wreg[CD][4];
#pragma unroll
  for (int d = 0; d < CD; ++d) {
    float4 v = *reinterpret_cast<const float4*>(Wout + d * DIMX + 4 * t);
    wreg[d][0] = v.x; wreg[d][1] = v.y; wreg[d][2] = v.z; wreg[d][3] = v.w;
  }
  float4 b4 = *reinterpret_cast<const float4*>(bout + 4 * t);

  float histr[16];
#pragma unroll
  for (int k = 0; k < 16; ++k) histr[k] = 0.f;
  float pse_acc = 0.f, com_acc = 0.f;

  for (int i = 0; i < 16; ++i) {
    const int row = blockIdx.x * 16 + i;
    if (t < CD) {
      float hv = h[(size_t)row * CD + t];
      sh[t] = hv;
      // x = 20*h ; e2 = exp(-2|x|) ; H_d = log(1+e2) + 2|x| e2/(1+e2)
      float ax  = fabsf(20.f * hv);
      float e2  = __expf(-2.f * ax);
      float inv = 1.f / (1.f + e2);
      pse_acc  += __logf(1.f + e2) + 2.f * ax * e2 * inv;
      sq[t]     = (hv > 0.f) ? inv : e2 * inv;     // sigmoid(40 h)
      float dd  = fabsf(hv) - 1.f;                  // (h - sign(h))^2
      com_acc  += dd * dd;
    }
    __syncthreads();

    // out row: b_out + sum_d sign(h_d) * W_out[d,:]
    float o0 = b4.x, o1 = b4.y, o2 = b4.z, o3 = b4.w;
#pragma unroll
    for (int d = 0; d < CD; ++d) {
      float s = (sh[d] > 0.f) ? 1.f : -1.f;
      o0 = fmaf(s, wreg[d][0], o0);
      o1 = fmaf(s, wreg[d][1], o1);
      o2 = fmaf(s, wreg[d][2], o2);
      o3 = fmaf(s, wreg[d][3], o3);
    }
    reinterpret_cast<float4*>(out + (size_t)row * DIMX)[t] = make_float4(o0, o1, o2, o3);

    if (t == 0) {
      int idx = 0;
#pragma unroll
      for (int d = 0; d < CD; ++d) idx |= (sh[d] > 0.f) ? (1 << d) : 0;
      oidx[row] = (float)idx;   // exact in f32 (<= 4095)
    }

    // factorized softmax halves: A over low 6 bits (wave 0), B over high 6 (wave 1)
    if (t < 64) {
      float p = 1.f;
#pragma unroll
      for (int d = 0; d < 6; ++d) { float q = sq[d]; p *= ((t >> d) & 1) ? q : 1.f - q; }
      sA[t] = p;
    } else if (t < 128) {
      const int u = t - 64;
      float p = 1.f;
#pragma unroll
      for (int d = 0; d < 6; ++d) { float q = sq[6 + d]; p *= ((u >> d) & 1) ? q : 1.f - q; }
      sB[u] = p;
    }
    __syncthreads();

    // thread t accumulates p_j for j = 16t..16t+15 : jHi = t>>2 const, jLo = 16(t&3)+k
    float bb = sB[t >> 2];
    const float4* ap = reinterpret_cast<const float4*>(&sA[(t & 3) * 16]);
#pragma unroll
    for (int k = 0; k < 4; ++k) {
      float4 av = ap[k];
      histr[4 * k + 0] = fmaf(bb, av.x, histr[4 * k + 0]);
      histr[4 * k + 1] = fmaf(bb, av.y, histr[4 * k + 1]);
      histr[4 * k + 2] = fmaf(bb, av.z, histr[4 * k + 2]);
      histr[4 * k + 3] = fmaf(bb, av.w, histr[4 * k + 3]);
    }
    __syncthreads();
  }

#pragma unroll
  for (int k = 0; k < 16; ++k) atomicAdd(&hist[t * 16 + k], histr[k]);

  if (t < CD) { sr0[t] = pse_acc; sr1[t] = com_acc; }
  __syncthreads();
  if (t == 0) {
    float s1 = 0.f, s2 = 0.f;
#pragma unroll
    for (int d = 0; d < CD; ++d) { s1 += sr0[d]; s2 += sr1[d]; }
    atomicAdd(pse, s1);
    atomicAdd(com, s2);
  }
}

// ---------------- Kernel C: final scalar reduction -> aux_loss ----------------
__global__ __launch_bounds__(256) void k_final(
    const float* __restrict__ hist, const float* __restrict__ pse,
    const float* __restrict__ com, float* __restrict__ aux)
{
  const int t = threadIdx.x;
  float local = 0.f;
#pragma unroll
  for (int k = 0; k < 16; ++k) {
    float a = hist[t * 16 + k] * (1.f / 16384.f);
    local -= a * __logf(a + 1e-10f);
  }
#pragma unroll
  for (int ofs = 1; ofs < 64; ofs <<= 1) local += __shfl_xor(local, ofs, 64);
  __shared__ float sw[4];
  if ((t & 63) == 0) sw[t >> 6] = local;
  __syncthreads();
  if (t == 0) {
    float cbe = sw[0] + sw[1] + sw[2] + sw[3];
    // aux = per_sample_entropy - codebook_entropy + commit_loss
    aux[0] = pse[0] * (1.f / 16384.f) - cbe + com[0] * (1.f / 196608.f);
  }
}

extern "C" void kernel_launch(void* const* d_in, const int* in_sizes, int n_in,
                              void* d_out, int out_size, void* d_ws, size_t ws_size,
                              hipStream_t stream)
{
  const float* x    = (const float*)d_in[0];
  const float* Win  = (const float*)d_in[1];
  const float* bin  = (const float*)d_in[2];
  const float* Wout = (const float*)d_in[3];
  const float* bout = (const float*)d_in[4];

  float* out  = (float*)d_out;                       // [16384 x 1024]
  float* oidx = out + (size_t)M_ROWS * DIMX;         // [16384] as float
  float* aux  = oidx + M_ROWS;                       // [1]

  float* ws   = (float*)d_ws;
  float* h    = ws;                                  // 196608 floats
  float* hist = ws + (size_t)M_ROWS * CD;            // 4096 floats
  float* pse  = hist + KCB;                          // 1
  float* com  = pse + 1;                             // 1

  hipMemsetAsync(hist, 0, (KCB + 2) * sizeof(float), stream);
  k_hproj<<<M_ROWS / 4, 256, 0, stream>>>(x, Win, bin, h);
  k_main <<<M_ROWS / 16, 256, 0, stream>>>(h, Wout, bout, out, oidx, hist, pse, com);
  k_final<<<1, 256, 0, stream>>>(hist, pse, com, aux);
}

// Round 2
// 163.232 us; speedup vs baseline: 3.0788x; 3.0788x over previous
//
#include <hip/hip_runtime.h>

#define M_ROWS 16384
#define DIMX   1024
#define CD     12
#define KCB    4096

// ---------------- Kernel A: h = x @ W_in + b_in  (wave per row) ----------------
// UNCHANGED from round 1: its summation order gives exact index match (absmax 0).
__global__ __launch_bounds__(256) void k_hproj(
    const float* __restrict__ x, const float* __restrict__ Win,
    const float* __restrict__ bin, float* __restrict__ h)
{
  __shared__ __align__(16) float w[DIMX * CD];
  for (int i = threadIdx.x; i < DIMX * CD / 4; i += 256)
    reinterpret_cast<float4*>(w)[i] = reinterpret_cast<const float4*>(Win)[i];
  __syncthreads();

  const int wave = threadIdx.x >> 6;
  const int lane = threadIdx.x & 63;
  const int row  = blockIdx.x * 4 + wave;

  const float4* xr = reinterpret_cast<const float4*>(x + (size_t)row * DIMX);
  float acc[CD];
#pragma unroll
  for (int d = 0; d < CD; ++d) acc[d] = 0.f;

#pragma unroll
  for (int k = 0; k < 4; ++k) {
    float4 xv = xr[lane + 64 * k];
    const float* wp = &w[(lane + 64 * k) * 4 * CD];
    float xe[4] = {xv.x, xv.y, xv.z, xv.w};
#pragma unroll
    for (int e = 0; e < 4; ++e)
#pragma unroll
      for (int d = 0; d < CD; ++d)
        acc[d] = fmaf(xe[e], wp[e * CD + d], acc[d]);
  }
#pragma unroll
  for (int ofs = 1; ofs < 64; ofs <<= 1)
#pragma unroll
    for (int d = 0; d < CD; ++d)
      acc[d] += __shfl_xor(acc[d], ofs, 64);

  if (lane == 0) {
#pragma unroll
    for (int d = 0; d < CD; ++d)
      h[(size_t)row * CD + d] = acc[d] + bin[d];
  }
}

// ------- Kernel B: barrier-free, atomic-free per-row fused pass -------
// Thread t owns output cols 4t..4t+3 and codebook entries j = 16t..16t+15.
// All per-row state (h, q) computed redundantly per thread from uniform loads.
__global__ __launch_bounds__(256) void k_main(
    const float* __restrict__ h, const float* __restrict__ Wout,
    const float* __restrict__ bout, float* __restrict__ out,
    float* __restrict__ oidx, float* __restrict__ hist_part,
    float* __restrict__ pse, float* __restrict__ com, int rows_pb)
{
  const int t   = threadIdx.x;
  const int bid = blockIdx.x;
  const int row0 = bid * rows_pb;

  // W_out fragment for my 4 columns (48 regs)
  float wreg[CD][4];
#pragma unroll
  for (int d = 0; d < CD; ++d) {
    float4 v = *reinterpret_cast<const float4*>(Wout + d * DIMX + 4 * t);
    wreg[d][0] = v.x; wreg[d][1] = v.y; wreg[d][2] = v.z; wreg[d][3] = v.w;
  }
  float4 b4 = *reinterpret_cast<const float4*>(bout + 4 * t);

  float histr[16];
#pragma unroll
  for (int k = 0; k < 16; ++k) histr[k] = 0.f;
  float pse_acc = 0.f, com_acc = 0.f;

  for (int i = 0; i < rows_pb; ++i) {
    const int row = row0 + i;
    const float* hr = h + (size_t)row * CD;   // block-uniform -> scalar loads
    float hv[CD];
    {
      float4 a = reinterpret_cast<const float4*>(hr)[0];
      float4 b = reinterpret_cast<const float4*>(hr)[1];
      float4 c = reinterpret_cast<const float4*>(hr)[2];
      hv[0]=a.x; hv[1]=a.y; hv[2]=a.z; hv[3]=a.w;
      hv[4]=b.x; hv[5]=b.y; hv[6]=b.z; hv[7]=b.w;
      hv[8]=c.x; hv[9]=c.y; hv[10]=c.z; hv[11]=c.w;
    }

    // ---- out row: b_out + sum_d sign(h_d) * W_out[d,:] ----
    float o0 = b4.x, o1 = b4.y, o2 = b4.z, o3 = b4.w;
#pragma unroll
    for (int d = 0; d < CD; ++d) {
      float s = (hv[d] > 0.f) ? 1.f : -1.f;
      o0 = fmaf(s, wreg[d][0], o0);
      o1 = fmaf(s, wreg[d][1], o1);
      o2 = fmaf(s, wreg[d][2], o2);
      o3 = fmaf(s, wreg[d][3], o3);
    }
    reinterpret_cast<float4*>(out + (size_t)row * DIMX)[t] = make_float4(o0, o1, o2, o3);

    // ---- q_d = sigmoid(40 h_d); entropy + commit (accumulated once, t-redundant) ----
    float q[CD];
#pragma unroll
    for (int d = 0; d < CD; ++d) {
      float ax  = fabsf(40.f * hv[d]);
      float e2  = __expf(-ax);                 // exp(-40|h|)
      float inv = 1.f / (1.f + e2);
      pse_acc  += __logf(1.f + e2) + ax * e2 * inv;
      q[d]      = (hv[d] > 0.f) ? inv : e2 * inv;
      float dd  = fabsf(hv[d]) - 1.f;
      com_acc  += dd * dd;
    }

    if (t == 0) {
      int idx = 0;
#pragma unroll
      for (int d = 0; d < CD; ++d) idx |= (hv[d] > 0.f) ? (1 << d) : 0;
      oidx[row] = (float)idx;
    }

    // ---- factorized p for my 16 codes: P4 over dims 0..3, const factor for 4..11 ----
    float P[16];
    P[0] = 1.f;
#pragma unroll
    for (int d = 0; d < 4; ++d) {
      const float qd = q[d], nq = 1.f - qd;
#pragma unroll
      for (int j2 = 0; j2 < (1 << d); ++j2) {
        P[j2 + (1 << d)] = P[j2] * qd;
        P[j2]            = P[j2] * nq;
      }
    }
    float c = (t & 1) ? q[4] : 1.f - q[4];
    c      *= (t & 2) ? q[5] : 1.f - q[5];
    const int u = t >> 2;
#pragma unroll
    for (int d = 0; d < 6; ++d)
      c *= ((u >> d) & 1) ? q[6 + d] : 1.f - q[6 + d];

#pragma unroll
    for (int k = 0; k < 16; ++k) histr[k] = fmaf(c, P[k], histr[k]);
  }

  // plain coalesced store of this block's partial histogram (no atomics)
  float4* hp = reinterpret_cast<float4*>(hist_part + (size_t)bid * KCB + t * 16);
#pragma unroll
  for (int k = 0; k < 4; ++k)
    hp[k] = make_float4(histr[4*k], histr[4*k+1], histr[4*k+2], histr[4*k+3]);

  if (t == 0) { atomicAdd(pse, pse_acc); atomicAdd(com, com_acc); }
}

// ---------------- Kernel C1: reduce partial hists -> codebook entropy ----------------
__global__ __launch_bounds__(256) void k_hist_reduce(
    const float* __restrict__ hist_part, float* __restrict__ cbe, int nblk)
{
  const int j = blockIdx.x * 256 + threadIdx.x;   // 0..4095
  float acc = 0.f;
#pragma unroll 4
  for (int b = 0; b < nblk; ++b) acc += hist_part[(size_t)b * KCB + j];
  float a = acc * (1.f / 16384.f);
  float term = -a * __logf(a + 1e-10f);
#pragma unroll
  for (int ofs = 1; ofs < 64; ofs <<= 1) term += __shfl_xor(term, ofs, 64);
  __shared__ float sw[4];
  if ((threadIdx.x & 63) == 0) sw[threadIdx.x >> 6] = term;
  __syncthreads();
  if (threadIdx.x == 0)
    atomicAdd(cbe, sw[0] + sw[1] + sw[2] + sw[3]);
}

// ---------------- Kernel C2: combine scalars -> aux_loss ----------------
__global__ void k_aux(const float* __restrict__ pse, const float* __restrict__ com,
                      const float* __restrict__ cbe, float* __restrict__ aux)
{
  aux[0] = pse[0] * (1.f / 16384.f) - cbe[0] + com[0] * (1.f / 196608.f);
}

extern "C" void kernel_launch(void* const* d_in, const int* in_sizes, int n_in,
                              void* d_out, int out_size, void* d_ws, size_t ws_size,
                              hipStream_t stream)
{
  const float* x    = (const float*)d_in[0];
  const float* Win  = (const float*)d_in[1];
  const float* bin  = (const float*)d_in[2];
  const float* Wout = (const float*)d_in[3];
  const float* bout = (const float*)d_in[4];

  float* out  = (float*)d_out;                       // [16384 x 1024]
  float* oidx = out + (size_t)M_ROWS * DIMX;         // [16384]
  float* aux  = oidx + M_ROWS;                       // [1]

  float* ws    = (float*)d_ws;
  float* h     = ws;                                 // 196608 floats
  float* scal  = ws + (size_t)M_ROWS * CD;           // pse, com, cbe
  float* pse   = scal;
  float* com   = scal + 1;
  float* cbe   = scal + 2;
  float* hist_part = scal + 16;                      // nblk * 4096 floats

  // pick block count so partial hists fit the workspace (floor 64)
  int nblk = 512;
  while (nblk > 64 &&
         ((size_t)M_ROWS * CD + 16 + (size_t)nblk * KCB) * 4 > ws_size)
    nblk >>= 1;
  const int rows_pb = M_ROWS / nblk;

  hipMemsetAsync(scal, 0, 3 * sizeof(float), stream);
  k_hproj<<<M_ROWS / 4, 256, 0, stream>>>(x, Win, bin, h);
  k_main <<<nblk, 256, 0, stream>>>(h, Wout, bout, out, oidx, hist_part, pse, com, rows_pb);
  k_hist_reduce<<<KCB / 256, 256, 0, stream>>>(hist_part, cbe, nblk);
  k_aux<<<1, 1, 0, stream>>>(pse, com, cbe, aux);
}

// Round 3
// 111.545 us; speedup vs baseline: 4.5054x; 1.4634x over previous
//
#include <hip/hip_runtime.h>

#define M_ROWS 16384
#define DIMX   1024
#define CD     12
#define KCB    4096
#define PADW   60   // padded dwords per float4-position fragment (48 data + 12 pad)

// ---------- Kernel A: h = x @ W_in + b_in ; writes h and oidx ----------
// Arithmetic (FMA order k,e,d; butterfly ofs 1..32; +bin at end) is bit-identical
// to the round-1/2 version that produced exact index match.
__global__ __launch_bounds__(256, 2) void k_hproj(
    const float* __restrict__ x, const float* __restrict__ Win,
    const float* __restrict__ bin, float* __restrict__ h, float* __restrict__ oidx)
{
  __shared__ __align__(16) float w[256 * PADW];   // 60 KB, conflict-free stride
  for (int f = threadIdx.x; f < 256 * 12; f += 256) {
    const int P = f / 12, c = f % 12;
    float4 v = reinterpret_cast<const float4*>(Win)[f];
    *reinterpret_cast<float4*>(&w[P * PADW + 4 * c]) = v;
  }
  __syncthreads();

  const int wave = threadIdx.x >> 6;
  const int lane = threadIdx.x & 63;
  const int g    = blockIdx.x * 4 + wave;         // 0..2047, 8 rows per wave

  float bb[CD];
#pragma unroll
  for (int d = 0; d < CD; ++d) bb[d] = bin[d];

  for (int it = 0; it < 4; ++it) {                // 2 rows per iteration
    const int row0 = g * 8 + it * 2;
    const float4* xr0 = reinterpret_cast<const float4*>(x + (size_t)row0 * DIMX);
    const float4* xr1 = reinterpret_cast<const float4*>(x + (size_t)(row0 + 1) * DIMX);
    float a0[CD], a1[CD];
#pragma unroll
    for (int d = 0; d < CD; ++d) { a0[d] = 0.f; a1[d] = 0.f; }

#pragma unroll
    for (int k = 0; k < 4; ++k) {
      const int P = lane + 64 * k;
      float4 xv0 = xr0[P];
      float4 xv1 = xr1[P];
      const float4* wf = reinterpret_cast<const float4*>(&w[P * PADW]);
      float4 wq[12];
#pragma unroll
      for (int c = 0; c < 12; ++c) wq[c] = wf[c];
      const float* wfl = reinterpret_cast<const float*>(wq);
      float xe0[4] = {xv0.x, xv0.y, xv0.z, xv0.w};
      float xe1[4] = {xv1.x, xv1.y, xv1.z, xv1.w};
#pragma unroll
      for (int e = 0; e < 4; ++e)
#pragma unroll
        for (int d = 0; d < CD; ++d) {
          const float wv = wfl[e * CD + d];
          a0[d] = fmaf(xe0[e], wv, a0[d]);
          a1[d] = fmaf(xe1[e], wv, a1[d]);
        }
    }
#pragma unroll
    for (int ofs = 1; ofs < 64; ofs <<= 1)
#pragma unroll
      for (int d = 0; d < CD; ++d) {
        a0[d] += __shfl_xor(a0[d], ofs, 64);
        a1[d] += __shfl_xor(a1[d], ofs, 64);
      }

    if (lane == 0) {
      int i0 = 0, i1 = 0;
#pragma unroll
      for (int d = 0; d < CD; ++d) {
        const float h0 = a0[d] + bb[d];
        const float h1 = a1[d] + bb[d];
        h[(size_t)row0 * CD + d]       = h0;
        h[(size_t)(row0 + 1) * CD + d] = h1;
        i0 |= (h0 > 0.f) ? (1 << d) : 0;
        i1 |= (h1 > 0.f) ? (1 << d) : 0;
      }
      oidx[row0]     = (float)i0;
      oidx[row0 + 1] = (float)i1;
    }
  }
}

// ---------- Kernel B: out = sign(h) @ W_out + b_out (signs from oidx) ----------
__global__ __launch_bounds__(256, 2) void k_out(
    const float* __restrict__ Wout, const float* __restrict__ bout,
    const float* __restrict__ oidx, float* __restrict__ out, int rows_pb)
{
  const int t = threadIdx.x;
  float wreg[CD][4];
#pragma unroll
  for (int d = 0; d < CD; ++d) {
    float4 v = *reinterpret_cast<const float4*>(Wout + d * DIMX + 4 * t);
    wreg[d][0] = v.x; wreg[d][1] = v.y; wreg[d][2] = v.z; wreg[d][3] = v.w;
  }
  float4 b4 = *reinterpret_cast<const float4*>(bout + 4 * t);

  const int row0 = blockIdx.x * rows_pb;
  for (int i = 0; i < rows_pb; ++i) {
    const int row = row0 + i;
    const int idx = (int)oidx[row];               // block-uniform scalar load
    float o0 = b4.x, o1 = b4.y, o2 = b4.z, o3 = b4.w;
#pragma unroll
    for (int d = 0; d < CD; ++d) {
      const float s = ((idx >> d) & 1) ? 1.f : -1.f;
      o0 = fmaf(s, wreg[d][0], o0);
      o1 = fmaf(s, wreg[d][1], o1);
      o2 = fmaf(s, wreg[d][2], o2);
      o3 = fmaf(s, wreg[d][3], o3);
    }
    reinterpret_cast<float4*>(out + (size_t)row * DIMX)[t] = make_float4(o0, o1, o2, o3);
  }
}

// ---------- Kernel C: entropy + commit + factorized histogram, wave per row ----------
// Lane owns codes j = m*64 + lane (m=0..63): p_j = A_lane * C[m&7] * D[m>>3].
__global__ __launch_bounds__(256) void k_ent(
    const float* __restrict__ h, float* __restrict__ hist_part,
    float* __restrict__ pse, float* __restrict__ com, int rpw)
{
  const int lane = threadIdx.x & 63;
  const int slab = blockIdx.x * 4 + (threadIdx.x >> 6);

  float acc[64];
#pragma unroll
  for (int m = 0; m < 64; ++m) acc[m] = 0.f;
  float pse_acc = 0.f, com_acc = 0.f;

  const int r0 = slab * rpw;
  for (int i = 0; i < rpw; ++i) {
    const int row = r0 + i;
    float qv = 0.f;
    if (lane < CD) {
      const float hv = h[(size_t)row * CD + lane];
      const float ax  = fabsf(40.f * hv);
      const float e2  = __expf(-ax);
      const float s1  = 1.f + e2;
      const float inv = 1.f / s1;
      qv = (hv > 0.f) ? inv : e2 * inv;           // sigmoid(40 h)
      pse_acc += __logf(s1) + ax * e2 * inv;      // per-dim entropy term
      const float dd = fabsf(hv) - 1.f;
      com_acc += dd * dd;
    }
    float qb[CD];
#pragma unroll
    for (int d = 0; d < CD; ++d) qb[d] = __shfl(qv, d, 64);

    float A = 1.f;
#pragma unroll
    for (int d = 0; d < 6; ++d) A *= ((lane >> d) & 1) ? qb[d] : (1.f - qb[d]);

    float C[8], D[8];
    C[0] = 1.f; D[0] = 1.f;
#pragma unroll
    for (int d = 0; d < 3; ++d) {
      const float qc = qb[6 + d], qd = qb[9 + d];
#pragma unroll
      for (int j2 = 0; j2 < (1 << d); ++j2) {
        C[j2 + (1 << d)] = C[j2] * qc; C[j2] *= (1.f - qc);
        D[j2 + (1 << d)] = D[j2] * qd; D[j2] *= (1.f - qd);
      }
    }
    float E[8];
#pragma unroll
    for (int k = 0; k < 8; ++k) E[k] = A * C[k];
#pragma unroll
    for (int m = 0; m < 64; ++m)
      acc[m] = fmaf(E[m & 7], D[m >> 3], acc[m]);
  }

  float* hp = hist_part + (size_t)slab * KCB;
#pragma unroll 8
  for (int m = 0; m < 64; ++m) hp[m * 64 + lane] = acc[m];

#pragma unroll
  for (int ofs = 1; ofs < 64; ofs <<= 1) {
    pse_acc += __shfl_xor(pse_acc, ofs, 64);
    com_acc += __shfl_xor(com_acc, ofs, 64);
  }
  if (lane == 0) { atomicAdd(pse, pse_acc); atomicAdd(com, com_acc); }
}

// ---------- Kernel D1: partial slab reduction (256 blocks) ----------
__global__ __launch_bounds__(256) void k_hr1(
    const float* __restrict__ hist_part, float* __restrict__ part2,
    int nslab)
{
  const int j     = (blockIdx.x & 15) * 256 + threadIdx.x;
  const int chunk = blockIdx.x >> 4;              // 0..15
  const int per   = nslab >> 4;
  const int b0    = chunk * per;
  float acc = 0.f;
#pragma unroll 4
  for (int b = 0; b < per; ++b)
    acc += hist_part[(size_t)(b0 + b) * KCB + j];
  part2[(size_t)chunk * KCB + j] = acc;
}

// ---------- Kernel D2: final codebook entropy ----------
__global__ __launch_bounds__(256) void k_hr2(
    const float* __restrict__ part2, float* __restrict__ cbe)
{
  const int j = blockIdx.x * 256 + threadIdx.x;
  float acc = 0.f;
#pragma unroll
  for (int c = 0; c < 16; ++c) acc += part2[(size_t)c * KCB + j];
  const float a = acc * (1.f / 16384.f);
  float term = -a * __logf(a + 1e-10f);
#pragma unroll
  for (int ofs = 1; ofs < 64; ofs <<= 1) term += __shfl_xor(term, ofs, 64);
  __shared__ float sw[4];
  if ((threadIdx.x & 63) == 0) sw[threadIdx.x >> 6] = term;
  __syncthreads();
  if (threadIdx.x == 0) atomicAdd(cbe, sw[0] + sw[1] + sw[2] + sw[3]);
}

// ---------- Kernel E: combine scalars ----------
__global__ void k_aux(const float* __restrict__ pse, const float* __restrict__ com,
                      const float* __restrict__ cbe, float* __restrict__ aux)
{
  aux[0] = pse[0] * (1.f / 16384.f) - cbe[0] + com[0] * (1.f / 196608.f);
}

extern "C" void kernel_launch(void* const* d_in, const int* in_sizes, int n_in,
                              void* d_out, int out_size, void* d_ws, size_t ws_size,
                              hipStream_t stream)
{
  const float* x    = (const float*)d_in[0];
  const float* Win  = (const float*)d_in[1];
  const float* bin  = (const float*)d_in[2];
  const float* Wout = (const float*)d_in[3];
  const float* bout = (const float*)d_in[4];

  float* out  = (float*)d_out;                       // [16384 x 1024]
  float* oidx = out + (size_t)M_ROWS * DIMX;         // [16384]
  float* aux  = oidx + M_ROWS;                       // [1]

  float* ws        = (float*)d_ws;
  float* h         = ws;                             // 196608 floats
  float* scal      = ws + (size_t)M_ROWS * CD;       // pse, com, cbe (pad 16)
  float* pse       = scal;
  float* com       = scal + 1;
  float* cbe       = scal + 2;
  float* part2     = scal + 16;                      // 16 * 4096 floats
  float* hist_part = part2 + 16 * KCB;               // nslab * 4096 floats

  int nslab = 1024;
  while (nslab > 256 &&
         ((size_t)M_ROWS * CD + 16 + 16 * KCB + (size_t)nslab * KCB) * 4 > ws_size)
    nslab >>= 1;
  const int rpw = M_ROWS / nslab;

  hipMemsetAsync(scal, 0, 3 * sizeof(float), stream);
  k_hproj<<<512, 256, 0, stream>>>(x, Win, bin, h, oidx);
  k_ent  <<<nslab / 4, 256, 0, stream>>>(h, hist_part, pse, com, rpw);   // h still L2-warm
  k_out  <<<512, 256, 0, stream>>>(Wout, bout, oidx, out, M_ROWS / 512);
  k_hr1  <<<256, 256, 0, stream>>>(hist_part, part2, nslab);
  k_hr2  <<<KCB / 256, 256, 0, stream>>>(part2, cbe);
  k_aux  <<<1, 1, 0, stream>>>(pse, com, cbe, aux);
}